// Round 17
// baseline (5316.430 us; speedup 1.0000x reference)
//
#include <hip/hip_runtime.h>
#include <hip/hip_bf16.h>

typedef __bf16 bf16x8 __attribute__((ext_vector_type(8)));
typedef ushort ushort8 __attribute__((ext_vector_type(8)));
typedef float  f32x4  __attribute__((ext_vector_type(4)));

#define LR_C 0.001f
#define VMCNT(n) asm volatile("s_waitcnt vmcnt(" #n ")" ::: "memory")
#define CFENCE() asm volatile("" ::: "memory")

__device__ __forceinline__ float sigf(float x){ return 1.0f/(1.0f + __expf(-x)); }
__device__ __forceinline__ ushort f2bu(float x){ __hip_bfloat16 h = __float2bfloat16(x); return *(ushort*)&h; }
__device__ __forceinline__ float bu2f(ushort u){ __hip_bfloat16 h = *(__hip_bfloat16*)&u; return __bfloat162float(h); }

__device__ __forceinline__ void gload_lds16(const void* g, void* l){
  __builtin_amdgcn_global_load_lds(
      (const __attribute__((address_space(1))) void*)g,
      (__attribute__((address_space(3))) void*)l, 16, 0, 0);
}

// ---------------- prep kernels ----------------

__global__ void k_cvt_bf16(__hip_bfloat16* dst, const float* src, int n){
  int i = blockIdx.x*256 + threadIdx.x;
  if (i < n) dst[i] = __float2bfloat16(src[i]);
}

__global__ void k_cvt_pad(__hip_bfloat16* dst, const float* src, int rows, int cs, int cd){
  int i = blockIdx.x*256 + threadIdx.x;
  if (i >= rows*cd) return;
  int r = i / cd, c = i % cd;
  float v = (c < cs) ? src[r*cs + c] : 0.0f;
  dst[i] = __float2bfloat16(v);
}

// dst[n][j] (n<sc, stride dstride, j>=sr zero) = src[j][n]
__global__ void k_transpose(__hip_bfloat16* dst, const float* src, int sr, int sc, int dstride){
  int i = blockIdx.x*256 + threadIdx.x;
  if (i >= sc*dstride) return;
  int n = i / dstride, j = i % dstride;
  float v = (j < sr) ? src[j*sc + n] : 0.0f;
  dst[i] = __float2bfloat16(v);
}

// state init: sf (bf16) = s, A (bf16) = sig(s)
__global__ void k_init_state(ushort* sf, __hip_bfloat16* A, const float* s, int n){
  int i = blockIdx.x*256 + threadIdx.x;
  if (i >= n) return;
  float v = s[i];
  sf[i] = f2bu(v);
  A[i] = __float2bfloat16(sigf(v));
}

// s3: 8192x10 -> s3f (f32, stride 10), A3 (stride 32, cols 10..31 = 0)
__global__ void k_init_s3(float* s3f, __hip_bfloat16* A3, const float* s3){
  int i = blockIdx.x*256 + threadIdx.x;
  if (i >= 8192*32) return;
  int b = i >> 5, c = i & 31;
  if (c < 10){
    float v = s3[b*10 + c];
    s3f[b*10 + c] = v;
    A3[i] = __float2bfloat16(sigf(v));
  } else {
    A3[i] = __float2bfloat16(0.0f);
  }
}

__global__ void k_zero_bf16(__hip_bfloat16* p, int n){
  int i = blockIdx.x*256 + threadIdx.x;
  if (i < n) p[i] = __float2bfloat16(0.0f);
}

__global__ void k_copy_f32(float* dst, const float* src, int n){
  int i = blockIdx.x*256 + threadIdx.x;
  if (i < n) dst[i] = src[i];
}

// ---------------- 128x128 / BK=32 / 4-wave NT GEMM, 3-deep pipelined ----
// (proven core — verbatim)

__device__ __forceinline__ void gemm128(
    const ushort* __restrict__ A, const ushort* __restrict__ B,
    int lda, int ldb, int K, int Nclamp,
    int brow, int bcol, int t, ushort* As, ushort* Bs, f32x4 (&acc)[4][4])
{
  const int w    = t >> 6;
  const int lane = t & 63;
  const int wr   = (w >> 1) * 64;
  const int wc   = (w & 1) * 64;
  const int fr   = lane & 15;
  const int ks   = (lane >> 4) * 8;
  const int rks  = ks ^ ((fr & 3) << 3);

#pragma unroll
  for (int m=0;m<4;m++)
#pragma unroll
    for (int n=0;n<4;n++){ acc[m][n][0]=0.f; acc[m][n][1]=0.f; acc[m][n][2]=0.f; acc[m][n][3]=0.f; }

  const int arow = t >> 2;
  const int acol = ((t & 3) * 8) ^ ((arow & 3) << 3);
  const ushort* gA  = A + (size_t)(brow + arow) * lda + acol;
  const ushort* gA2 = gA + (size_t)64 * lda;
  int rb  = bcol + arow;      if (rb  > Nclamp-1) rb  = Nclamp-1;
  int rb2 = bcol + 64 + arow; if (rb2 > Nclamp-1) rb2 = Nclamp-1;
  const ushort* gB  = B + (size_t)rb  * ldb + acol;
  const ushort* gB2 = B + (size_t)rb2 * ldb + acol;

  auto STAGE = [&](int buf, int k0){
    ushort* Ab = As + buf*4096;
    ushort* Bb = Bs + buf*4096;
    gload_lds16(gA  + k0, Ab + w*512);
    gload_lds16(gA2 + k0, Ab + 2048 + w*512);
    gload_lds16(gB  + k0, Bb + w*512);
    gload_lds16(gB2 + k0, Bb + 2048 + w*512);
  };

  const int nt = K >> 5;
  STAGE(0, 0);
  if (nt > 1) STAGE(1, 32);
  if (nt > 2) STAGE(2, 64);

  int cur = 0;
  for (int tk = 0; tk < nt; ++tk){
    const int rem = nt - 1 - tk;
    if (rem >= 2)      { VMCNT(8); }
    else if (rem == 1) { VMCNT(4); }
    else               { VMCNT(0); }
    __builtin_amdgcn_s_barrier();
    CFENCE();

    const ushort* Ab = As + cur*4096;
    const ushort* Bb = Bs + cur*4096;
    bf16x8 af[4], bfv[4];
#pragma unroll
    for (int m=0;m<4;m++) af[m]  = *(const bf16x8*)&Ab[(wr + m*16 + fr)*32 + rks];
#pragma unroll
    for (int n=0;n<4;n++) bfv[n] = *(const bf16x8*)&Bb[(wc + n*16 + fr)*32 + rks];
#pragma unroll
    for (int m=0;m<4;m++)
#pragma unroll
      for (int n=0;n<4;n++)
        acc[m][n] = __builtin_amdgcn_mfma_f32_16x16x32_bf16(af[m], bfv[n], acc[m][n], 0, 0, 0);

    CFENCE();
    __builtin_amdgcn_s_barrier();
    CFENCE();
    if (tk + 3 < nt) STAGE(cur, (tk+3)*32);
    cur = cur + 1; if (cur == 3) cur = 0;
  }
}

// stage C fragments -> LDS bf16 [128][128], col XOR-swizzled by (row&3)<<3
__device__ __forceinline__ void stageC(const f32x4 (&acc)[4][4], int t, ushort* Cs){
  const int w = t >> 6, lane = t & 63;
  const int wr = (w >> 1) * 64, wc = (w & 1) * 64;
  const int fr = lane & 15, r4 = (lane >> 4) * 4;
#pragma unroll
  for (int m=0;m<4;m++){
#pragma unroll
    for (int j=0;j<4;j++){
      int r = wr + m*16 + r4 + j;
      int sw = (r & 3) << 3;
#pragma unroll
      for (int n=0;n<4;n++){
        int c = wc + n*16 + fr;
        Cs[r*128 + (c ^ sw)] = f2bu(acc[m][n][j]);
      }
    }
  }
}

// XCD-aware block map
__device__ __forceinline__ void blockmap(int lid, int nbx, int& brow, int& bcol){
  int by = (lid & 7) + 8 * ((lid >> 3) / nbx);
  int bx = (lid >> 3) % nbx;
  brow = by * 128; bcol = bx * 128;
}

// ---------------- fused dispatch kernels (r12 topology) ----------------
// D1 = { P1 [0,448) | U2 [448,704) | U3 [704,768) }
// D2 = { P2->U1 [0,512) | P3 [512,768) }   (p1b eliminated; e1 carried in regs)

__global__ __launch_bounds__(256, 3)
void fusedD1(int base,
             const ushort* __restrict__ A1, const ushort* __restrict__ W1b,
             const ushort* __restrict__ inb, ushort* __restrict__ e0, float* p0out,
             const ushort* __restrict__ e1b, const ushort* __restrict__ W2T,
             ushort* __restrict__ s2f, const ushort* __restrict__ e2b,
             ushort* __restrict__ A2,
             const ushort* __restrict__ W3T, float* __restrict__ s3f,
             ushort* __restrict__ A3)
{
  __shared__ __align__(16) ushort lds[3*4096*2];   // 48 KB
  ushort* As = lds;
  ushort* Bs = lds + 3*4096;
  ushort* Cs = lds;                                // overlay after K-loop
  const int bid = blockIdx.x + base;
  const int t = threadIdx.x;
  const int lr = t >> 4, lc = (t & 15) * 8;
  f32x4 acc[4][4];

  if (bid < 448){                      // P1: e0 = inb - A1@W1b^T
    int brow, bcol; blockmap(bid, 7, brow, bcol);
    gemm128(A1, W1b, 1024, 1024, 1024, 784, brow, bcol, t, As, Bs, acc);
    stageC(acc, t, Cs); __syncthreads();
#pragma unroll
    for (int it=0; it<8; ++it){
      int r = it*16 + lr, gr = brow + r, gc = bcol + lc;
      if (gc < 784){
        ushort8 ib = *(const ushort8*)&inb[(size_t)gr*784 + gc];   // global first
        ushort8 g  = *(const ushort8*)&Cs[r*128 + (lc ^ ((r&3)<<3))];
        ushort8 e; float pv0,pv1,pv2,pv3,pv4,pv5,pv6,pv7;
        pv0=bu2f(g[0]); pv1=bu2f(g[1]); pv2=bu2f(g[2]); pv3=bu2f(g[3]);
        pv4=bu2f(g[4]); pv5=bu2f(g[5]); pv6=bu2f(g[6]); pv7=bu2f(g[7]);
        e[0]=f2bu(bu2f(ib[0])-pv0); e[1]=f2bu(bu2f(ib[1])-pv1);
        e[2]=f2bu(bu2f(ib[2])-pv2); e[3]=f2bu(bu2f(ib[3])-pv3);
        e[4]=f2bu(bu2f(ib[4])-pv4); e[5]=f2bu(bu2f(ib[5])-pv5);
        e[6]=f2bu(bu2f(ib[6])-pv6); e[7]=f2bu(bu2f(ib[7])-pv7);
        *(ushort8*)&e0[(size_t)gr*800 + gc] = e;
        if (p0out){
          f32x4 lo = {pv0,pv1,pv2,pv3}, hi = {pv4,pv5,pv6,pv7};
          *(f32x4*)&p0out[(size_t)gr*784 + gc]     = lo;
          *(f32x4*)&p0out[(size_t)gr*784 + gc + 4] = hi;
        }
      }
    }
  } else if (bid < 704){               // U2: s2 += LR*(-e2 + sig'(s2)*(e1@W2))
    int brow, bcol; blockmap(bid - 448, 4, brow, bcol);
    gemm128(e1b, W2T, 1024, 1024, 1024, 512, brow, bcol, t, As, Bs, acc);
    stageC(acc, t, Cs); __syncthreads();
#pragma unroll
    for (int it=0; it<8; ++it){
      int r = it*16 + lr, gr = brow + r, gc = bcol + lc;
      size_t ix = (size_t)gr*512 + gc;
      ushort8 sv = *(const ushort8*)&s2f[ix];                      // globals first
      ushort8 e2 = *(const ushort8*)&e2b[ix];
      ushort8 g = *(const ushort8*)&Cs[r*128 + (lc ^ ((r&3)<<3))];
      ushort8 a2o, so;
#pragma unroll
      for (int k=0;k<8;k++){
        float s = bu2f(sv[k]); float a = sigf(s);
        float ap = a*(1.0f-a);
        float d = LR_C*(-bu2f(e2[k]) + ap*bu2f(g[k]));
        so[k] = f2bu(s + d);
        a2o[k] = f2bu(a + ap*d);       // Taylor: sig(s+d) ≈ a + a(1-a)d, err<5e-8
      }
      *(ushort8*)&s2f[ix] = so;
      *(ushort8*)&A2[ix] = a2o;
    }
  } else {                             // U3 (tiny): frag-domain epilogue, s3 f32
    int brow = (bid - 704) * 128;
    gemm128(e2b, W3T, 512, 512, 512, 16, brow, 0, t, As, Bs, acc);
    const int w = t >> 6, lane = t & 63;
    const int wr = (w >> 1) * 64, wc = (w & 1) * 64;
    const int fr = lane & 15, r4 = (lane >> 4) * 4;
    const int orow0 = brow + wr + r4, ocol0 = wc + fr;
#pragma unroll
    for (int m=0;m<4;m++)
#pragma unroll
      for (int n=0;n<4;n++){
        int col = ocol0 + n*16;
        if (col >= 10) continue;
#pragma unroll
        for (int j=0;j<4;j++){
          int row = orow0 + m*16 + j;
          float s = s3f[(size_t)row*10 + col];
          float a = sigf(s);
          float ap = a*(1.0f-a);
          float d = LR_C*(ap*acc[m][n][j]);
          s3f[(size_t)row*10 + col] = s + d;
          A3[(size_t)row*32 + col] = f2bu(a + ap*d);
        }
      }
  }
}

__global__ __launch_bounds__(256, 3)
void fusedD2(const ushort* __restrict__ A2, const ushort* __restrict__ W2b,
             const ushort* __restrict__ e0, const ushort* __restrict__ W1T,
             ushort* __restrict__ s1f, ushort* __restrict__ A1,
             ushort* __restrict__ e1b,
             const ushort* __restrict__ A3, const ushort* __restrict__ W3b,
             const ushort* __restrict__ s2f, ushort* __restrict__ e2b)
{
  __shared__ __align__(16) ushort lds[3*4096*2];   // 48 KB
  ushort* As = lds;
  ushort* Bs = lds + 3*4096;
  ushort* Cs = lds;
  const int bid = blockIdx.x;
  const int t = threadIdx.x;
  const int lr = t >> 4, lc = (t & 15) * 8;
  f32x4 acc[4][4];

  if (bid < 512){                      // P2 (e1 computed here, kept in regs) -> U1
    int brow, bcol; blockmap(bid, 8, brow, bcol);
    gemm128(A2, W2b, 512, 512, 512, 1024, brow, bcol, t, As, Bs, acc);
    stageC(acc, t, Cs); __syncthreads();
    ushort8 e1r[8], svr[8];
#pragma unroll
    for (int it=0; it<8; ++it){
      int r = it*16 + lr, gr = brow + r, gc = bcol + lc;
      size_t ix = (size_t)gr*1024 + gc;
      ushort8 sv = *(const ushort8*)&s1f[ix];                      // old s1
      ushort8 g = *(const ushort8*)&Cs[r*128 + (lc ^ ((r&3)<<3))]; // p1
      ushort8 e1o;
#pragma unroll
      for (int k=0;k<8;k++) e1o[k] = f2bu(bu2f(sv[k]) - bu2f(g[k]));
      *(ushort8*)&e1b[ix] = e1o;       // e1 for next cycle's U2
      e1r[it] = e1o;
      svr[it] = sv;
    }
    __syncthreads();                   // Cs free before gemm2 staging
    gemm128(e0, W1T, 800, 800, 800, 1024, brow, bcol, t, As, Bs, acc);
    stageC(acc, t, Cs); __syncthreads();
#pragma unroll
    for (int it=0; it<8; ++it){
      int r = it*16 + lr, gr = brow + r, gc = bcol + lc;
      size_t ix = (size_t)gr*1024 + gc;
      ushort8 g = *(const ushort8*)&Cs[r*128 + (lc ^ ((r&3)<<3))];
      ushort8 sv = svr[it], e1 = e1r[it];
      ushort8 a1o, so;
#pragma unroll
      for (int k=0;k<8;k++){
        float s = bu2f(sv[k]);
        float a = sigf(s);
        float ap = a*(1.0f-a);
        float d = LR_C*(-bu2f(e1[k]) + ap*bu2f(g[k]));
        so[k] = f2bu(s + d);
        a1o[k] = f2bu(a + ap*d);       // Taylor
      }
      *(ushort8*)&s1f[ix] = so;
      *(ushort8*)&A1[ix]  = a1o;
    }
  } else {                             // P3: e2 = s2 - A3@W3b^T
    int brow, bcol; blockmap(bid - 512, 4, brow, bcol);
    gemm128(A3, W3b, 32, 32, 32, 512, brow, bcol, t, As, Bs, acc);
    stageC(acc, t, Cs); __syncthreads();
#pragma unroll
    for (int it=0; it<8; ++it){
      int r = it*16 + lr, gr = brow + r, gc = bcol + lc;
      size_t ix = (size_t)gr*512 + gc;
      ushort8 sv = *(const ushort8*)&s2f[ix];                      // global first
      ushort8 g = *(const ushort8*)&Cs[r*128 + (lc ^ ((r&3)<<3))];
      ushort8 e2o;
#pragma unroll
      for (int k=0;k<8;k++) e2o[k] = f2bu(bu2f(sv[k]) - bu2f(g[k]));
      *(ushort8*)&e2b[ix] = e2o;
    }
  }
}

// ---------------- host orchestration ----------------

extern "C" void kernel_launch(void* const* d_in, const int* in_sizes, int n_in,
                              void* d_out, int out_size, void* d_ws, size_t ws_size,
                              hipStream_t stream) {
  const float* input = (const float*)d_in[0];
  const float* s1    = (const float*)d_in[1];
  const float* s2    = (const float*)d_in[2];
  const float* s3    = (const float*)d_in[3];
  const float* W1    = (const float*)d_in[4];
  const float* W2    = (const float*)d_in[5];
  const float* W3    = (const float*)d_in[6];
  float* out = (float*)d_out;

  char* ws = (char*)d_ws;
  size_t off = 0;
  auto take = [&](size_t bytes)->char*{
    char* p = ws + off;
    off = (off + bytes + 255) & ~(size_t)255;
    return p;
  };

  ushort* s1f = (ushort*)take(8192ull*1024*2);   // bf16 state
  ushort* s2f = (ushort*)take(8192ull*512*2);    // bf16 state
  float*  s3f = (float*)take(8192ull*10*4);      // f32 (checked output)
  __hip_bfloat16* A1  = (__hip_bfloat16*)take(8192ull*1024*2);
  __hip_bfloat16* A2  = (__hip_bfloat16*)take(8192ull*512*2);
  __hip_bfloat16* A3  = (__hip_bfloat16*)take(8192ull*32*2);
  __hip_bfloat16* e0  = (__hip_bfloat16*)take(8192ull*800*2);
  __hip_bfloat16* e1b = (__hip_bfloat16*)take(8192ull*1024*2);
  __hip_bfloat16* e2b = (__hip_bfloat16*)take(8192ull*512*2);
  __hip_bfloat16* inb = (__hip_bfloat16*)take(8192ull*784*2);
  __hip_bfloat16* W1b = (__hip_bfloat16*)take(784ull*1024*2);
  __hip_bfloat16* W2b = (__hip_bfloat16*)take(1024ull*512*2);
  __hip_bfloat16* W3b = (__hip_bfloat16*)take(512ull*32*2);
  __hip_bfloat16* W1T = (__hip_bfloat16*)take(1024ull*800*2);
  __hip_bfloat16* W2T = (__hip_bfloat16*)take(512ull*1024*2);
  __hip_bfloat16* W3T = (__hip_bfloat16*)take(16ull*512*2);

  auto cdiv = [](int a, int b){ return (a + b - 1) / b; };

  // --- prep ---
  k_cvt_bf16 <<<cdiv(8192*784,256),256,0,stream>>>(inb, input, 8192*784);
  k_cvt_bf16 <<<cdiv(784*1024,256),256,0,stream>>>(W1b, W1, 784*1024);
  k_cvt_bf16 <<<cdiv(1024*512,256),256,0,stream>>>(W2b, W2, 1024*512);
  k_cvt_pad  <<<cdiv(512*32,256),256,0,stream>>>(W3b, W3, 512, 10, 32);
  k_transpose<<<cdiv(1024*800,256),256,0,stream>>>(W1T, W1, 784, 1024, 800);
  k_transpose<<<cdiv(512*1024,256),256,0,stream>>>(W2T, W2, 1024, 512, 1024);
  k_zero_bf16<<<cdiv(16*512,256),256,0,stream>>>(W3T, 16*512);
  k_transpose<<<cdiv(10*512,256),256,0,stream>>>(W3T, W3, 512, 10, 512);
  k_init_state<<<cdiv(8192*1024,256),256,0,stream>>>(s1f, A1, s1, 8192*1024);
  k_init_state<<<cdiv(8192*512,256),256,0,stream>>>(s2f, A2, s2, 8192*512);
  k_init_s3  <<<cdiv(8192*32,256),256,0,stream>>>(s3f, A3, s3);
  k_zero_bf16<<<cdiv(8192*800,256),256,0,stream>>>(e0, 8192*800);   // K-pad cols 784..799

  // --- 60 cycles, 2 dispatches each (r12 topology) ---
  for (int c = 0; c < 60; ++c){
    float* p0_dst = (c == 59) ? (out + 8192*10) : nullptr;
    if (c == 0){
      fusedD1<<<448, 256, 0, stream>>>(0, (const ushort*)A1, (const ushort*)W1b,
          (const ushort*)inb, (ushort*)e0, p0_dst,
          (const ushort*)e1b, (const ushort*)W2T, s2f, (const ushort*)e2b,
          (ushort*)A2, (const ushort*)W3T, s3f, (ushort*)A3);
    } else {
      fusedD1<<<768, 256, 0, stream>>>(0, (const ushort*)A1, (const ushort*)W1b,
          (const ushort*)inb, (ushort*)e0, p0_dst,
          (const ushort*)e1b, (const ushort*)W2T, s2f, (const ushort*)e2b,
          (ushort*)A2, (const ushort*)W3T, s3f, (ushort*)A3);
    }
    fusedD2<<<768, 256, 0, stream>>>((const ushort*)A2, (const ushort*)W2b,
        (const ushort*)e0, (const ushort*)W1T, s1f, (ushort*)A1, (ushort*)e1b,
        (const ushort*)A3, (const ushort*)W3b, (const ushort*)s2f, (ushort*)e2b);
  }
  // trailing U2(59), U3(59)
  fusedD1<<<320, 256, 0, stream>>>(448, (const ushort*)A1, (const ushort*)W1b,
      (const ushort*)inb, (ushort*)e0, nullptr,
      (const ushort*)e1b, (const ushort*)W2T, s2f, (const ushort*)e2b,
      (ushort*)A2, (const ushort*)W3T, s3f, (ushort*)A3);

  k_copy_f32<<<cdiv(8192*10,256),256,0,stream>>>(out, s3f, 8192*10);
}

// Round 18
// 4726.214 us; speedup vs baseline: 1.1249x; 1.1249x over previous
//
#include <hip/hip_runtime.h>
#include <hip/hip_bf16.h>

typedef __bf16 bf16x8 __attribute__((ext_vector_type(8)));
typedef ushort ushort8 __attribute__((ext_vector_type(8)));
typedef float  f32x4  __attribute__((ext_vector_type(4)));

#define LR_C 0.001f
#define VMCNT(n) asm volatile("s_waitcnt vmcnt(" #n ")" ::: "memory")
#define CFENCE() asm volatile("" ::: "memory")

__device__ __forceinline__ float sigf(float x){ return 1.0f/(1.0f + __expf(-x)); }
__device__ __forceinline__ ushort f2bu(float x){ __hip_bfloat16 h = __float2bfloat16(x); return *(ushort*)&h; }
__device__ __forceinline__ float bu2f(ushort u){ __hip_bfloat16 h = *(__hip_bfloat16*)&u; return __bfloat162float(h); }

__device__ __forceinline__ void gload_lds16(const void* g, void* l){
  __builtin_amdgcn_global_load_lds(
      (const __attribute__((address_space(1))) void*)g,
      (__attribute__((address_space(3))) void*)l, 16, 0, 0);
}

// ---------------- prep kernels ----------------

__global__ void k_cvt_bf16(__hip_bfloat16* dst, const float* src, int n){
  int i = blockIdx.x*256 + threadIdx.x;
  if (i < n) dst[i] = __float2bfloat16(src[i]);
}

__global__ void k_cvt_pad(__hip_bfloat16* dst, const float* src, int rows, int cs, int cd){
  int i = blockIdx.x*256 + threadIdx.x;
  if (i >= rows*cd) return;
  int r = i / cd, c = i % cd;
  float v = (c < cs) ? src[r*cs + c] : 0.0f;
  dst[i] = __float2bfloat16(v);
}

// dst[n][j] (n<sc, stride dstride, j>=sr zero) = src[j][n]
__global__ void k_transpose(__hip_bfloat16* dst, const float* src, int sr, int sc, int dstride){
  int i = blockIdx.x*256 + threadIdx.x;
  if (i >= sc*dstride) return;
  int n = i / dstride, j = i % dstride;
  float v = (j < sr) ? src[j*sc + n] : 0.0f;
  dst[i] = __float2bfloat16(v);
}

// state init: sf (bf16) = s, A (bf16) = sig(s)
__global__ void k_init_state(ushort* sf, __hip_bfloat16* A, const float* s, int n){
  int i = blockIdx.x*256 + threadIdx.x;
  if (i >= n) return;
  float v = s[i];
  sf[i] = f2bu(v);
  A[i] = __float2bfloat16(sigf(v));
}

// s3: 8192x10 -> s3f (f32, stride 10), A3 (stride 32, cols 10..31 = 0)
__global__ void k_init_s3(float* s3f, __hip_bfloat16* A3, const float* s3){
  int i = blockIdx.x*256 + threadIdx.x;
  if (i >= 8192*32) return;
  int b = i >> 5, c = i & 31;
  if (c < 10){
    float v = s3[b*10 + c];
    s3f[b*10 + c] = v;
    A3[i] = __float2bfloat16(sigf(v));
  } else {
    A3[i] = __float2bfloat16(0.0f);
  }
}

__global__ void k_zero_bf16(__hip_bfloat16* p, int n){
  int i = blockIdx.x*256 + threadIdx.x;
  if (i < n) p[i] = __float2bfloat16(0.0f);
}

__global__ void k_copy_f32(float* dst, const float* src, int n){
  int i = blockIdx.x*256 + threadIdx.x;
  if (i < n) dst[i] = src[i];
}

// ---------------- 128x128 / BK=32 / 4-wave NT GEMM, 3-deep pipelined ----
// (proven core — verbatim)

__device__ __forceinline__ void gemm128(
    const ushort* __restrict__ A, const ushort* __restrict__ B,
    int lda, int ldb, int K, int Nclamp,
    int brow, int bcol, int t, ushort* As, ushort* Bs, f32x4 (&acc)[4][4])
{
  const int w    = t >> 6;
  const int lane = t & 63;
  const int wr   = (w >> 1) * 64;
  const int wc   = (w & 1) * 64;
  const int fr   = lane & 15;
  const int ks   = (lane >> 4) * 8;
  const int rks  = ks ^ ((fr & 3) << 3);

#pragma unroll
  for (int m=0;m<4;m++)
#pragma unroll
    for (int n=0;n<4;n++){ acc[m][n][0]=0.f; acc[m][n][1]=0.f; acc[m][n][2]=0.f; acc[m][n][3]=0.f; }

  const int arow = t >> 2;
  const int acol = ((t & 3) * 8) ^ ((arow & 3) << 3);
  const ushort* gA  = A + (size_t)(brow + arow) * lda + acol;
  const ushort* gA2 = gA + (size_t)64 * lda;
  int rb  = bcol + arow;      if (rb  > Nclamp-1) rb  = Nclamp-1;
  int rb2 = bcol + 64 + arow; if (rb2 > Nclamp-1) rb2 = Nclamp-1;
  const ushort* gB  = B + (size_t)rb  * ldb + acol;
  const ushort* gB2 = B + (size_t)rb2 * ldb + acol;

  auto STAGE = [&](int buf, int k0){
    ushort* Ab = As + buf*4096;
    ushort* Bb = Bs + buf*4096;
    gload_lds16(gA  + k0, Ab + w*512);
    gload_lds16(gA2 + k0, Ab + 2048 + w*512);
    gload_lds16(gB  + k0, Bb + w*512);
    gload_lds16(gB2 + k0, Bb + 2048 + w*512);
  };

  const int nt = K >> 5;
  STAGE(0, 0);
  if (nt > 1) STAGE(1, 32);
  if (nt > 2) STAGE(2, 64);

  int cur = 0;
  for (int tk = 0; tk < nt; ++tk){
    const int rem = nt - 1 - tk;
    if (rem >= 2)      { VMCNT(8); }
    else if (rem == 1) { VMCNT(4); }
    else               { VMCNT(0); }
    __builtin_amdgcn_s_barrier();
    CFENCE();

    const ushort* Ab = As + cur*4096;
    const ushort* Bb = Bs + cur*4096;
    bf16x8 af[4], bfv[4];
#pragma unroll
    for (int m=0;m<4;m++) af[m]  = *(const bf16x8*)&Ab[(wr + m*16 + fr)*32 + rks];
#pragma unroll
    for (int n=0;n<4;n++) bfv[n] = *(const bf16x8*)&Bb[(wc + n*16 + fr)*32 + rks];
#pragma unroll
    for (int m=0;m<4;m++)
#pragma unroll
      for (int n=0;n<4;n++)
        acc[m][n] = __builtin_amdgcn_mfma_f32_16x16x32_bf16(af[m], bfv[n], acc[m][n], 0, 0, 0);

    CFENCE();
    __builtin_amdgcn_s_barrier();
    CFENCE();
    if (tk + 3 < nt) STAGE(cur, (tk+3)*32);
    cur = cur + 1; if (cur == 3) cur = 0;
  }
}

// stage C fragments -> LDS bf16 [128][128], col XOR-swizzled by (row&3)<<3
__device__ __forceinline__ void stageC(const f32x4 (&acc)[4][4], int t, ushort* Cs){
  const int w = t >> 6, lane = t & 63;
  const int wr = (w >> 1) * 64, wc = (w & 1) * 64;
  const int fr = lane & 15, r4 = (lane >> 4) * 4;
#pragma unroll
  for (int m=0;m<4;m++){
#pragma unroll
    for (int j=0;j<4;j++){
      int r = wr + m*16 + r4 + j;
      int sw = (r & 3) << 3;
#pragma unroll
      for (int n=0;n<4;n++){
        int c = wc + n*16 + fr;
        Cs[r*128 + (c ^ sw)] = f2bu(acc[m][n][j]);
      }
    }
  }
}

// XCD-aware block map
__device__ __forceinline__ void blockmap(int lid, int nbx, int& brow, int& bcol){
  int by = (lid & 7) + 8 * ((lid >> 3) / nbx);
  int bx = (lid >> 3) % nbx;
  brow = by * 128; bcol = bx * 128;
}

// ---------------- fused dispatch kernels (r12 topology) ----------------
// D1 = { P1 [0,448) | U2 [448,704) | U3 [704,768) }
// D2 = { P2->U1 [0,512) | P3 [512,768) }   (p1b eliminated; e1 via e1b memory)

__global__ __launch_bounds__(256, 3)
void fusedD1(int base,
             const ushort* __restrict__ A1, const ushort* __restrict__ W1b,
             const ushort* __restrict__ inb, ushort* __restrict__ e0, float* p0out,
             const ushort* __restrict__ e1b, const ushort* __restrict__ W2T,
             ushort* __restrict__ s2f, const ushort* __restrict__ e2b,
             ushort* __restrict__ A2,
             const ushort* __restrict__ W3T, float* __restrict__ s3f,
             ushort* __restrict__ A3)
{
  __shared__ __align__(16) ushort lds[3*4096*2];   // 48 KB
  ushort* As = lds;
  ushort* Bs = lds + 3*4096;
  ushort* Cs = lds;                                // overlay after K-loop
  const int bid = blockIdx.x + base;
  const int t = threadIdx.x;
  const int lr = t >> 4, lc = (t & 15) * 8;
  f32x4 acc[4][4];

  if (bid < 448){                      // P1: e0 = inb - A1@W1b^T
    int brow, bcol; blockmap(bid, 7, brow, bcol);
    gemm128(A1, W1b, 1024, 1024, 1024, 784, brow, bcol, t, As, Bs, acc);
    stageC(acc, t, Cs); __syncthreads();
#pragma unroll
    for (int it=0; it<8; ++it){
      int r = it*16 + lr, gr = brow + r, gc = bcol + lc;
      if (gc < 784){
        ushort8 ib = *(const ushort8*)&inb[(size_t)gr*784 + gc];   // global first
        ushort8 g  = *(const ushort8*)&Cs[r*128 + (lc ^ ((r&3)<<3))];
        ushort8 e; float pv0,pv1,pv2,pv3,pv4,pv5,pv6,pv7;
        pv0=bu2f(g[0]); pv1=bu2f(g[1]); pv2=bu2f(g[2]); pv3=bu2f(g[3]);
        pv4=bu2f(g[4]); pv5=bu2f(g[5]); pv6=bu2f(g[6]); pv7=bu2f(g[7]);
        e[0]=f2bu(bu2f(ib[0])-pv0); e[1]=f2bu(bu2f(ib[1])-pv1);
        e[2]=f2bu(bu2f(ib[2])-pv2); e[3]=f2bu(bu2f(ib[3])-pv3);
        e[4]=f2bu(bu2f(ib[4])-pv4); e[5]=f2bu(bu2f(ib[5])-pv5);
        e[6]=f2bu(bu2f(ib[6])-pv6); e[7]=f2bu(bu2f(ib[7])-pv7);
        *(ushort8*)&e0[(size_t)gr*800 + gc] = e;
        if (p0out){
          f32x4 lo = {pv0,pv1,pv2,pv3}, hi = {pv4,pv5,pv6,pv7};
          *(f32x4*)&p0out[(size_t)gr*784 + gc]     = lo;
          *(f32x4*)&p0out[(size_t)gr*784 + gc + 4] = hi;
        }
      }
    }
  } else if (bid < 704){               // U2: s2 += LR*(-e2 + sig'(s2)*(e1@W2))
    int brow, bcol; blockmap(bid - 448, 4, brow, bcol);
    gemm128(e1b, W2T, 1024, 1024, 1024, 512, brow, bcol, t, As, Bs, acc);
    stageC(acc, t, Cs); __syncthreads();
#pragma unroll
    for (int it=0; it<8; ++it){
      int r = it*16 + lr, gr = brow + r, gc = bcol + lc;
      size_t ix = (size_t)gr*512 + gc;
      ushort8 sv = *(const ushort8*)&s2f[ix];                      // globals first
      ushort8 e2 = *(const ushort8*)&e2b[ix];
      ushort8 g = *(const ushort8*)&Cs[r*128 + (lc ^ ((r&3)<<3))];
      ushort8 a2o, so;
#pragma unroll
      for (int k=0;k<8;k++){
        float s = bu2f(sv[k]); float a = sigf(s);
        float ap = a*(1.0f-a);
        float d = LR_C*(-bu2f(e2[k]) + ap*bu2f(g[k]));
        so[k] = f2bu(s + d);
        a2o[k] = f2bu(a + ap*d);       // Taylor: sig(s+d) ≈ a + a(1-a)d, err<5e-8
      }
      *(ushort8*)&s2f[ix] = so;
      *(ushort8*)&A2[ix] = a2o;
    }
  } else {                             // U3 (tiny): frag-domain epilogue, s3 f32
    int brow = (bid - 704) * 128;
    gemm128(e2b, W3T, 512, 512, 512, 16, brow, 0, t, As, Bs, acc);
    const int w = t >> 6, lane = t & 63;
    const int wr = (w >> 1) * 64, wc = (w & 1) * 64;
    const int fr = lane & 15, r4 = (lane >> 4) * 4;
    const int orow0 = brow + wr + r4, ocol0 = wc + fr;
#pragma unroll
    for (int m=0;m<4;m++)
#pragma unroll
      for (int n=0;n<4;n++){
        int col = ocol0 + n*16;
        if (col >= 10) continue;
#pragma unroll
        for (int j=0;j<4;j++){
          int row = orow0 + m*16 + j;
          float s = s3f[(size_t)row*10 + col];
          float a = sigf(s);
          float ap = a*(1.0f-a);
          float d = LR_C*(ap*acc[m][n][j]);
          s3f[(size_t)row*10 + col] = s + d;
          A3[(size_t)row*32 + col] = f2bu(a + ap*d);
        }
      }
  }
}

__global__ __launch_bounds__(256, 3)
void fusedD2(const ushort* __restrict__ A2, const ushort* __restrict__ W2b,
             const ushort* __restrict__ e0, const ushort* __restrict__ W1T,
             ushort* __restrict__ s1f, ushort* __restrict__ A1,
             ushort* __restrict__ e1b,
             const ushort* __restrict__ A3, const ushort* __restrict__ W3b,
             const ushort* __restrict__ s2f, ushort* __restrict__ e2b)
{
  __shared__ __align__(16) ushort lds[3*4096*2];   // 48 KB
  ushort* As = lds;
  ushort* Bs = lds + 3*4096;
  ushort* Cs = lds;
  const int bid = blockIdx.x;
  const int t = threadIdx.x;
  const int lr = t >> 4, lc = (t & 15) * 8;
  f32x4 acc[4][4];

  if (bid < 512){                      // P2 (e1 -> e1b) -> U1 (re-reads e1b, s1f)
    int brow, bcol; blockmap(bid, 8, brow, bcol);
    gemm128(A2, W2b, 512, 512, 512, 1024, brow, bcol, t, As, Bs, acc);
    stageC(acc, t, Cs); __syncthreads();
#pragma unroll
    for (int it=0; it<8; ++it){
      int r = it*16 + lr, gr = brow + r, gc = bcol + lc;
      size_t ix = (size_t)gr*1024 + gc;
      ushort8 sv = *(const ushort8*)&s1f[ix];                      // old s1
      ushort8 g = *(const ushort8*)&Cs[r*128 + (lc ^ ((r&3)<<3))]; // p1
      ushort8 e1o;
#pragma unroll
      for (int k=0;k<8;k++) e1o[k] = f2bu(bu2f(sv[k]) - bu2f(g[k]));
      *(ushort8*)&e1b[ix] = e1o;       // replaces the p1b write
    }
    __syncthreads();                   // Cs free before gemm2 staging
    gemm128(e0, W1T, 800, 800, 800, 1024, brow, bcol, t, As, Bs, acc);
    stageC(acc, t, Cs); __syncthreads();
#pragma unroll
    for (int it=0; it<8; ++it){
      int r = it*16 + lr, gr = brow + r, gc = bcol + lc;
      size_t ix = (size_t)gr*1024 + gc;
      ushort8 e1 = *(const ushort8*)&e1b[ix];                      // L2-hot re-read
      ushort8 sv = *(const ushort8*)&s1f[ix];                      // still old
      ushort8 g = *(const ushort8*)&Cs[r*128 + (lc ^ ((r&3)<<3))];
      ushort8 a1o, so;
#pragma unroll
      for (int k=0;k<8;k++){
        float s = bu2f(sv[k]);
        float a = sigf(s);
        float ap = a*(1.0f-a);
        float d = LR_C*(-bu2f(e1[k]) + ap*bu2f(g[k]));
        so[k] = f2bu(s + d);
        a1o[k] = f2bu(a + ap*d);       // Taylor
      }
      *(ushort8*)&s1f[ix] = so;
      *(ushort8*)&A1[ix]  = a1o;
    }
  } else {                             // P3: e2 = s2 - A3@W3b^T
    int brow, bcol; blockmap(bid - 512, 4, brow, bcol);
    gemm128(A3, W3b, 32, 32, 32, 512, brow, bcol, t, As, Bs, acc);
    stageC(acc, t, Cs); __syncthreads();
#pragma unroll
    for (int it=0; it<8; ++it){
      int r = it*16 + lr, gr = brow + r, gc = bcol + lc;
      size_t ix = (size_t)gr*512 + gc;
      ushort8 sv = *(const ushort8*)&s2f[ix];                      // global first
      ushort8 g = *(const ushort8*)&Cs[r*128 + (lc ^ ((r&3)<<3))];
      ushort8 e2o;
#pragma unroll
      for (int k=0;k<8;k++) e2o[k] = f2bu(bu2f(sv[k]) - bu2f(g[k]));
      *(ushort8*)&e2b[ix] = e2o;
    }
  }
}

// ---------------- host orchestration ----------------

extern "C" void kernel_launch(void* const* d_in, const int* in_sizes, int n_in,
                              void* d_out, int out_size, void* d_ws, size_t ws_size,
                              hipStream_t stream) {
  const float* input = (const float*)d_in[0];
  const float* s1    = (const float*)d_in[1];
  const float* s2    = (const float*)d_in[2];
  const float* s3    = (const float*)d_in[3];
  const float* W1    = (const float*)d_in[4];
  const float* W2    = (const float*)d_in[5];
  const float* W3    = (const float*)d_in[6];
  float* out = (float*)d_out;

  char* ws = (char*)d_ws;
  size_t off = 0;
  auto take = [&](size_t bytes)->char*{
    char* p = ws + off;
    off = (off + bytes + 255) & ~(size_t)255;
    return p;
  };

  ushort* s1f = (ushort*)take(8192ull*1024*2);   // bf16 state
  ushort* s2f = (ushort*)take(8192ull*512*2);    // bf16 state
  float*  s3f = (float*)take(8192ull*10*4);      // f32 (checked output)
  __hip_bfloat16* A1  = (__hip_bfloat16*)take(8192ull*1024*2);
  __hip_bfloat16* A2  = (__hip_bfloat16*)take(8192ull*512*2);
  __hip_bfloat16* A3  = (__hip_bfloat16*)take(8192ull*32*2);
  __hip_bfloat16* e0  = (__hip_bfloat16*)take(8192ull*800*2);
  __hip_bfloat16* e1b = (__hip_bfloat16*)take(8192ull*1024*2);
  __hip_bfloat16* e2b = (__hip_bfloat16*)take(8192ull*512*2);
  __hip_bfloat16* inb = (__hip_bfloat16*)take(8192ull*784*2);
  __hip_bfloat16* W1b = (__hip_bfloat16*)take(784ull*1024*2);
  __hip_bfloat16* W2b = (__hip_bfloat16*)take(1024ull*512*2);
  __hip_bfloat16* W3b = (__hip_bfloat16*)take(512ull*32*2);
  __hip_bfloat16* W1T = (__hip_bfloat16*)take(1024ull*800*2);
  __hip_bfloat16* W2T = (__hip_bfloat16*)take(512ull*1024*2);
  __hip_bfloat16* W3T = (__hip_bfloat16*)take(16ull*512*2);

  auto cdiv = [](int a, int b){ return (a + b - 1) / b; };

  // --- prep ---
  k_cvt_bf16 <<<cdiv(8192*784,256),256,0,stream>>>(inb, input, 8192*784);
  k_cvt_bf16 <<<cdiv(784*1024,256),256,0,stream>>>(W1b, W1, 784*1024);
  k_cvt_bf16 <<<cdiv(1024*512,256),256,0,stream>>>(W2b, W2, 1024*512);
  k_cvt_pad  <<<cdiv(512*32,256),256,0,stream>>>(W3b, W3, 512, 10, 32);
  k_transpose<<<cdiv(1024*800,256),256,0,stream>>>(W1T, W1, 784, 1024, 800);
  k_transpose<<<cdiv(512*1024,256),256,0,stream>>>(W2T, W2, 1024, 512, 1024);
  k_zero_bf16<<<cdiv(16*512,256),256,0,stream>>>(W3T, 16*512);
  k_transpose<<<cdiv(10*512,256),256,0,stream>>>(W3T, W3, 512, 10, 512);
  k_init_state<<<cdiv(8192*1024,256),256,0,stream>>>(s1f, A1, s1, 8192*1024);
  k_init_state<<<cdiv(8192*512,256),256,0,stream>>>(s2f, A2, s2, 8192*512);
  k_init_s3  <<<cdiv(8192*32,256),256,0,stream>>>(s3f, A3, s3);
  k_zero_bf16<<<cdiv(8192*800,256),256,0,stream>>>(e0, 8192*800);   // K-pad cols 784..799

  // --- 60 cycles, 2 dispatches each (r12 topology) ---
  for (int c = 0; c < 60; ++c){
    float* p0_dst = (c == 59) ? (out + 8192*10) : nullptr;
    if (c == 0){
      fusedD1<<<448, 256, 0, stream>>>(0, (const ushort*)A1, (const ushort*)W1b,
          (const ushort*)inb, (ushort*)e0, p0_dst,
          (const ushort*)e1b, (const ushort*)W2T, s2f, (const ushort*)e2b,
          (ushort*)A2, (const ushort*)W3T, s3f, (ushort*)A3);
    } else {
      fusedD1<<<768, 256, 0, stream>>>(0, (const ushort*)A1, (const ushort*)W1b,
          (const ushort*)inb, (ushort*)e0, p0_dst,
          (const ushort*)e1b, (const ushort*)W2T, s2f, (const ushort*)e2b,
          (ushort*)A2, (const ushort*)W3T, s3f, (ushort*)A3);
    }
    fusedD2<<<768, 256, 0, stream>>>((const ushort*)A2, (const ushort*)W2b,
        (const ushort*)e0, (const ushort*)W1T, s1f, (ushort*)A1, (ushort*)e1b,
        (const ushort*)A3, (const ushort*)W3b, (const ushort*)s2f, (ushort*)e2b);
  }
  // trailing U2(59), U3(59)
  fusedD1<<<320, 256, 0, stream>>>(448, (const ushort*)A1, (const ushort*)W1b,
      (const ushort*)inb, (ushort*)e0, nullptr,
      (const ushort*)e1b, (const ushort*)W2T, s2f, (const ushort*)e2b,
      (ushort*)A2, (const ushort*)W3T, s3f, (ushort*)A3);

  k_copy_f32<<<cdiv(8192*10,256),256,0,stream>>>(out, s3f, 8192*10);
}